// Round 12
// baseline (378.491 us; speedup 1.0000x reference)
//
#include <hip/hip_runtime.h>

// 2-layer GCN, CSR-gather, bf16 payloads, zero global atomics.
//   K1 [hist ∥ gemm, 1:1] -> scan1 -> scan2 -> scatter -> sort -> gather1
//   -> gather2f (gather + W2 matmul + pooled output).
// R12: gemm re-paired with hist (both dependency-free) so the scan doesn't
// sit between gemm and its overlap partner; scatter runs standalone (light,
// ~12 waves/CU of independent latency chains).  Gemm inner loop reverted to
// R10 form (R11 unroll x2 regressed 92->97.7us).
// Kept: 1:1 interleave (R9), 512-node buckets, packed 1-int bucket entries,
// bf16 h1 (R10), scan3g folded into consumers (R10), fused final (R10),
// uint-packed gathers (R11, ~10us win).

#define TPB 256
#define CHUNK 4096          // edges per hist/scatter block (1:1 with gemm blocks)
#define BK_SHIFT 9
#define NPB 512             // nodes per bucket = 1 << BK_SHIFT

__device__ __forceinline__ float bf2f(unsigned short u) {
    union { unsigned int i; float f; } v; v.i = ((unsigned int)u) << 16; return v.f;
}
__device__ __forceinline__ unsigned short f2bf(float f) {
    union { float f; unsigned int i; } v; v.f = f;
    unsigned int r = v.i + 0x7fff + ((v.i >> 16) & 1);   // RNE
    return (unsigned short)(r >> 16);
}

// K1: hist ∥ gemm, block-interleaved 1:1.
// hist role: counts[bk*nblk + blk] = #edges in chunk blk with col>>9 == bk.
// gemm role: h1b[n] = bf16(x[n] @ W1), one thread/node, W1 in LDS (R10 form).
__global__ __launch_bounds__(TPB) void hist_gemm_kernel(
        const int* __restrict__ col, int* __restrict__ counts,
        int E, int nblk, int nbuck,
        const float* __restrict__ x, const float* __restrict__ W1,
        unsigned short* __restrict__ h1b, int N, int nbg) {
    __shared__ int hist[NPB];
    __shared__ float w1s[128 * 16];
    int b = (int)blockIdx.x, t = threadIdx.x;
    int M = min(nblk, nbg);
    int role, id;
    if (b < 2 * M) { role = b & 1; id = b >> 1; }
    else           { role = (nblk > nbg) ? 0 : 1; id = b - M; }

    if (role == 0) {                         // hist
        for (int i = t; i < nbuck; i += TPB) hist[i] = 0;
        __syncthreads();
        int e0 = id * CHUNK;
        for (int i = t; i < CHUNK; i += TPB) {
            int e = e0 + i;
            if (e < E) atomicAdd(&hist[col[e] >> BK_SHIFT], 1);   // LDS atomic
        }
        __syncthreads();
        for (int i = t; i < nbuck; i += TPB) counts[i * nblk + id] = hist[i];
        return;
    }
    // gemm
    for (int i = t; i < 128 * 16; i += TPB) w1s[i] = W1[i];
    __syncthreads();
    int n = id * TPB + t;
    if (n >= N) return;
    const float4* xr = (const float4*)(x + (size_t)n * 128);
    float acc[16];
#pragma unroll
    for (int k = 0; k < 16; ++k) acc[k] = 0.f;
#pragma unroll 1
    for (int g = 0; g < 8; ++g) {
        float4 v0 = xr[g * 4 + 0], v1 = xr[g * 4 + 1];
        float4 v2 = xr[g * 4 + 2], v3 = xr[g * 4 + 3];
        float xv[16] = {v0.x, v0.y, v0.z, v0.w, v1.x, v1.y, v1.z, v1.w,
                        v2.x, v2.y, v2.z, v2.w, v3.x, v3.y, v3.z, v3.w};
#pragma unroll
        for (int cc = 0; cc < 16; ++cc) {
            const float4* w4 = (const float4*)&w1s[(g * 16 + cc) * 16];
            float4 wa = w4[0], wb = w4[1], wc = w4[2], wd = w4[3];
            float xc = xv[cc];
            acc[0]  = fmaf(xc, wa.x, acc[0]);  acc[1]  = fmaf(xc, wa.y, acc[1]);
            acc[2]  = fmaf(xc, wa.z, acc[2]);  acc[3]  = fmaf(xc, wa.w, acc[3]);
            acc[4]  = fmaf(xc, wb.x, acc[4]);  acc[5]  = fmaf(xc, wb.y, acc[5]);
            acc[6]  = fmaf(xc, wb.z, acc[6]);  acc[7]  = fmaf(xc, wb.w, acc[7]);
            acc[8]  = fmaf(xc, wc.x, acc[8]);  acc[9]  = fmaf(xc, wc.y, acc[9]);
            acc[10] = fmaf(xc, wc.z, acc[10]); acc[11] = fmaf(xc, wc.w, acc[11]);
            acc[12] = fmaf(xc, wd.x, acc[12]); acc[13] = fmaf(xc, wd.y, acc[13]);
            acc[14] = fmaf(xc, wd.z, acc[14]); acc[15] = fmaf(xc, wd.w, acc[15]);
        }
    }
    unsigned int u[8];
#pragma unroll
    for (int j = 0; j < 8; ++j)
        u[j] = (unsigned int)f2bf(acc[2 * j]) | ((unsigned int)f2bf(acc[2 * j + 1]) << 16);
    uint4* o = (uint4*)(h1b + (size_t)n * 16);
    o[0] = make_uint4(u[0], u[1], u[2], u[3]);
    o[1] = make_uint4(u[4], u[5], u[6], u[7]);
}

// scan1: per-256-block exclusive scan (counts in place), bsum[b]=block total
__global__ __launch_bounds__(TPB) void scan1_kernel(const int* __restrict__ in,
                                                    int* __restrict__ out,
                                                    int* __restrict__ bsum, int L) {
    __shared__ int s[TPB];
    int t = threadIdx.x;
    int i = blockIdx.x * TPB + t;
    int d = (i < L) ? in[i] : 0;
    s[t] = d; __syncthreads();
    for (int off = 1; off < TPB; off <<= 1) {
        int v = (t >= off) ? s[t - off] : 0;
        __syncthreads();
        s[t] += v;
        __syncthreads();
    }
    if (i < L) out[i] = s[t] - d;
    if (t == TPB - 1) bsum[blockIdx.x] = s[t];
}

// scan2: single-block exclusive scan of up to 2048 block sums (2 elems/thread)
__global__ __launch_bounds__(1024) void scan2_kernel(int* __restrict__ bsum, int nb) {
    __shared__ int s[1024];
    int t = threadIdx.x;
    int i0 = t * 2, i1 = t * 2 + 1;
    int v0 = (i0 < nb) ? bsum[i0] : 0;
    int v1 = (i1 < nb) ? bsum[i1] : 0;
    int pv = v0 + v1;
    s[t] = pv; __syncthreads();
    for (int off = 1; off < 1024; off <<= 1) {
        int u = (t >= off) ? s[t - off] : 0;
        __syncthreads();
        s[t] += u;
        __syncthreads();
    }
    int exc = s[t] - pv;
    if (i0 < nb) bsum[i0] = exc;
    if (i1 < nb) bsum[i1] = exc + v0;
}

// cbase[f] = counts[f] + bsum[f>>8]   (scan3g folded into consumers)
__device__ __forceinline__ int cbase_at(const int* counts, const int* bsum, int f) {
    return counts[f] + bsum[f >> 8];
}

// scatter (standalone): bucketed[pos] = (local_col<<18)|row via LDS cursors.
__global__ __launch_bounds__(TPB) void scatter_kernel(
        const int* __restrict__ row, const int* __restrict__ col,
        const int* __restrict__ counts, const int* __restrict__ bsum,
        int E, int nblk, int nbuck, int* __restrict__ bucketed) {
    __shared__ int cur[NPB];
    int id = (int)blockIdx.x, t = threadIdx.x;
    for (int i = t; i < nbuck; i += TPB)
        cur[i] = cbase_at(counts, bsum, i * nblk + id);
    __syncthreads();
    int e0 = id * CHUNK;
    for (int i = t; i < CHUNK; i += TPB) {
        int e = e0 + i;
        if (e < E) {
            int c = col[e];
            int pos = atomicAdd(&cur[c >> BK_SHIFT], 1);       // LDS atomic
            bucketed[pos] = ((c & (NPB - 1)) << 18) | row[e];
        }
    }
}

// sort: one block per 512-node bucket: counting sort, emit csr/offs/dinv,
// h1p = bf16(dinv * h1b).
__global__ __launch_bounds__(TPB) void sort_kernel(
        const int* __restrict__ bucketed,
        const int* __restrict__ counts, const int* __restrict__ bsum,
        int E, int nblk, int nbuck,
        int* __restrict__ csr, int* __restrict__ offs, float* __restrict__ dinv,
        const unsigned short* __restrict__ h1b, unsigned short* __restrict__ h1p, int N) {
    __shared__ int lhist[NPB];
    __shared__ int part[TPB];
    __shared__ float sdinv[NPB];
    int bk = blockIdx.x, t = threadIdx.x;
    int n0 = bk << BK_SHIFT;
    int n1 = min(n0 + NPB, N);
    int e0 = cbase_at(counts, bsum, bk * nblk);
    int e1 = (bk + 1 < nbuck) ? cbase_at(counts, bsum, (bk + 1) * nblk) : E;

    lhist[t] = 0; lhist[t + TPB] = 0;
    __syncthreads();
    for (int i = e0 + t; i < e1; i += TPB)
        atomicAdd(&lhist[bucketed[i] >> 18], 1);               // LDS atomic
    __syncthreads();

    int base = t * 2;
    int c0 = lhist[base], c1 = lhist[base + 1];
    int s = c0 + c1;
    part[t] = s;
    __syncthreads();
    for (int off = 1; off < TPB; off <<= 1) {
        int v = (t >= off) ? part[t - off] : 0;
        __syncthreads();
        part[t] += v;
        __syncthreads();
    }
    int o0 = e0 + part[t] - s;
    int o1 = o0 + c0;
    lhist[base] = o0; lhist[base + 1] = o1;
    sdinv[base]     = rsqrtf((float)c0 + 1.0f);
    sdinv[base + 1] = rsqrtf((float)c1 + 1.0f);
    int n = n0 + base;
    if (n + 0 < N) { offs[n + 0] = o0; dinv[n + 0] = sdinv[base]; }
    if (n + 1 < N) { offs[n + 1] = o1; dinv[n + 1] = sdinv[base + 1]; }
    __syncthreads();

    for (int i = e0 + t; i < e1; i += TPB) {
        int v = bucketed[i];
        int pos = atomicAdd(&lhist[v >> 18], 1);               // LDS atomic
        csr[pos] = v & 0x3FFFF;
    }
    int nq = (n1 - n0) * 4;                  // one quad (4 feats) per i
    for (int i = t; i < nq; i += TPB) {
        float dv = sdinv[i >> 2];
        uint2 u = ((const uint2*)h1b)[(size_t)n0 * 4 + i];
        float f0 = bf2f((unsigned short)(u.x & 0xffff));
        float f1 = bf2f((unsigned short)(u.x >> 16));
        float f2 = bf2f((unsigned short)(u.y & 0xffff));
        float f3 = bf2f((unsigned short)(u.y >> 16));
        ((ushort4*)h1p)[(size_t)n0 * 4 + i] =
            make_ushort4(f2bf(f0 * dv), f2bf(f1 * dv), f2bf(f2 * dv), f2bf(f3 * dv));
    }
    if (bk == 0 && t == 0) offs[N] = E;
}

// gather1: 16 lanes/node; uint-packed loads (2 edges per load instr per group);
// 32 edges/iteration; cross-half shfl_xor reduce.
// h2p[c] = bf16( dinv[c]*relu( dinv[c]*(sum h1p[src] + h1p[c]) + b1 ) )
__global__ __launch_bounds__(TPB) void gather1_kernel(const int* __restrict__ csr,
                                                      const int* __restrict__ offs,
                                                      const unsigned short* __restrict__ h1p,
                                                      const float* __restrict__ dinv,
                                                      const float* __restrict__ b1,
                                                      unsigned short* __restrict__ h2p, int N) {
    int t = threadIdx.x;
    int c = blockIdx.x * 16 + (t >> 4);
    int lane = t & 15;
    int half = lane >> 3;                    // which edge of the pair
    int kk = lane & 7;                       // feature pair: 2kk, 2kk+1
    if (c >= N) return;
    int p0 = offs[c], p1 = offs[c + 1];
    float a0 = 0.f, a1 = 0.f;
    for (int p = p0; p < p1; p += 32) {
        int s_lo = csr[min(p + lane, p1 - 1)];
        int s_hi = csr[min(p + 16 + lane, p1 - 1)];
        int rem = p1 - p;
        unsigned int u[16];
#pragma unroll
        for (int j = 0; j < 8; ++j) {
            int sj = __shfl(s_lo, 2 * j + half, 16);
            u[j] = *(const unsigned int*)&h1p[(size_t)sj * 16 + 2 * kk];
        }
#pragma unroll
        for (int j = 8; j < 16; ++j) {
            int sj = __shfl(s_hi, 2 * j + half - 16, 16);
            u[j] = *(const unsigned int*)&h1p[(size_t)sj * 16 + 2 * kk];
        }
#pragma unroll
        for (int j = 0; j < 16; ++j) {
            bool ok = (2 * j + half) < rem;
            a0 += ok ? bf2f((unsigned short)(u[j] & 0xffff)) : 0.f;
            a1 += ok ? bf2f((unsigned short)(u[j] >> 16)) : 0.f;
        }
    }
    a0 += __shfl_xor(a0, 8, 16);
    a1 += __shfl_xor(a1, 8, 16);
    if (half == 0) {
        float dc = dinv[c];
        unsigned int us = *(const unsigned int*)&h1p[(size_t)c * 16 + 2 * kk];
        float s0 = bf2f((unsigned short)(us & 0xffff));
        float s1 = bf2f((unsigned short)(us >> 16));
        float r0 = fmaf(dc, a0 + s0, b1[2 * kk]);
        float r1 = fmaf(dc, a1 + s1, b1[2 * kk + 1]);
        r0 = dc * fmaxf(r0, 0.f);
        r1 = dc * fmaxf(r1, 0.f);
        unsigned int w = (unsigned int)f2bf(r0) | ((unsigned int)f2bf(r1) << 16);
        *(unsigned int*)&h2p[(size_t)c * 16 + 2 * kk] = w;
    }
}

// gather2f: fused gather2 + W2 matmul + sorted-batch pooling.  Block = 64 nodes.
__global__ __launch_bounds__(TPB) void gather2f_kernel(
        const int* __restrict__ csr, const int* __restrict__ offs,
        const unsigned short* __restrict__ h2p, const float* __restrict__ dinv,
        const float* __restrict__ W2, const float* __restrict__ b2,
        const int* __restrict__ batch, float* __restrict__ out, int N) {
    __shared__ float w2s[16 * 64];
    __shared__ float asT[64 * 17];
    __shared__ float pool[64];
    int t = threadIdx.x;
    for (int i = t; i < 16 * 64; i += TPB) w2s[i] = W2[i];
    if (t < 64) pool[t] = 0.f;

    int n0 = blockIdx.x * 64;
    int nLast = min(n0 + 63, N - 1);
    int g0 = batch[n0];
    bool uniform = (batch[nLast] == g0);     // batch sorted

    // phase 1: gather (4 nodes per 16-lane group), uint-packed loads
    int grp = t >> 4, lane = t & 15;
    int half = lane >> 3, kk = lane & 7;
#pragma unroll 1
    for (int it = 0; it < 4; ++it) {
        int m = grp * 4 + it;
        int c = n0 + m;
        if (c < N) {
            int p0 = offs[c], p1 = offs[c + 1];
            float a0 = 0.f, a1 = 0.f;
            for (int p = p0; p < p1; p += 32) {
                int s_lo = csr[min(p + lane, p1 - 1)];
                int s_hi = csr[min(p + 16 + lane, p1 - 1)];
                int rem = p1 - p;
                unsigned int u[16];
#pragma unroll
                for (int j = 0; j < 8; ++j) {
                    int sj = __shfl(s_lo, 2 * j + half, 16);
                    u[j] = *(const unsigned int*)&h2p[(size_t)sj * 16 + 2 * kk];
                }
#pragma unroll
                for (int j = 8; j < 16; ++j) {
                    int sj = __shfl(s_hi, 2 * j + half - 16, 16);
                    u[j] = *(const unsigned int*)&h2p[(size_t)sj * 16 + 2 * kk];
                }
#pragma unroll
                for (int j = 0; j < 16; ++j) {
                    bool ok = (2 * j + half) < rem;
                    a0 += ok ? bf2f((unsigned short)(u[j] & 0xffff)) : 0.f;
                    a1 += ok ? bf2f((unsigned short)(u[j] >> 16)) : 0.f;
                }
            }
            a0 += __shfl_xor(a0, 8, 16);
            a1 += __shfl_xor(a1, 8, 16);
            if (half == 0) {
                float dc = dinv[c];
                unsigned int us = *(const unsigned int*)&h2p[(size_t)c * 16 + 2 * kk];
                float s0 = bf2f((unsigned short)(us & 0xffff));
                float s1 = bf2f((unsigned short)(us >> 16));
                asT[m * 17 + 2 * kk]     = dc * (a0 + s0);
                asT[m * 17 + 2 * kk + 1] = dc * (a1 + s1);
            }
        }
    }
    __syncthreads();

    // phase 2: wave w covers nodes n0+16w .. n0+16w+15
    int wave = t >> 6, j = t & 63;
    float w2reg[16];
#pragma unroll
    for (int kx = 0; kx < 16; ++kx) w2reg[kx] = w2s[kx * 64 + j];
    float b2j = b2[j];
    float val = 0.f;
    int g_cur = -1;
#pragma unroll 1
    for (int mi = 0; mi < 16; ++mi) {
        int m = wave * 16 + mi;
        int c = n0 + m;
        if (c >= N) break;
        const float* ar = &asT[m * 17];
        float y = b2j;
#pragma unroll
        for (int kx = 0; kx < 16; ++kx) y = fmaf(ar[kx], w2reg[kx], y);
        if (uniform) {
            val += y;
        } else {
            int g = batch[c];
            if (g != g_cur) {
                if (g_cur >= 0) atomicAdd(&out[(size_t)g_cur * 64 + j], val);
                val = 0.f;
                g_cur = g;
            }
            val += y;
        }
    }
    if (uniform) {
        atomicAdd(&pool[j], val);            // LDS, 4-way per address
        __syncthreads();
        if (t < 64) atomicAdd(&out[(size_t)g0 * 64 + t], pool[t]);
    } else {
        if (g_cur >= 0) atomicAdd(&out[(size_t)g_cur * 64 + j], val);
    }
}

static inline size_t align64(size_t v) { return (v + 63) & ~(size_t)63; }

extern "C" void kernel_launch(void* const* d_in, const int* in_sizes, int n_in,
                              void* d_out, int out_size, void* d_ws, size_t ws_size,
                              hipStream_t stream) {
    const float* x     = (const float*)d_in[0];
    const int*   ei    = (const int*)d_in[1];
    const int*   batch = (const int*)d_in[2];
    const float* W1    = (const float*)d_in[3];
    const float* b1    = (const float*)d_in[4];
    const float* W2    = (const float*)d_in[5];
    const float* b2    = (const float*)d_in[6];

    const int N = in_sizes[0] / 128;
    const int E = in_sizes[1] / 2;
    const int* row = ei;        // edge_index[0]
    const int* col = ei + E;    // edge_index[1]

    const int NBLK  = (E + CHUNK - 1) / CHUNK;       // 782
    const int NBUCK = (N + NPB - 1) / NPB;           // 391 (<=512)
    const int L     = NBUCK * NBLK;                  // 305762
    const int NBS   = (L + TPB - 1) / TPB;           // 1195 (<=2048 for scan2)
    const int NBG   = (N + TPB - 1) / TPB;           // 782

    char* p = (char*)d_ws;
    int*            counts   = (int*)p;            p += align64((size_t)L * 4);
    int*            bsum     = (int*)p;            p += align64(2048 * 4);
    int*            bucketed = (int*)p;            p += align64((size_t)E * 4);
    int*            csr      = (int*)p;            p += align64((size_t)E * 4);
    int*            offs     = (int*)p;            p += align64((size_t)(N + 1) * 4);
    float*          dinv     = (float*)p;          p += align64((size_t)N * 4);
    unsigned short* h1b      = (unsigned short*)p; p += align64((size_t)N * 16 * 2);
    unsigned short* h1p      = (unsigned short*)p; p += align64((size_t)N * 16 * 2);
    unsigned short* h2p      = (unsigned short*)p; p += align64((size_t)N * 16 * 2);
    float*          out      = (float*)d_out;

    hipMemsetAsync(out, 0, (size_t)out_size * sizeof(float), stream);

    hist_gemm_kernel<<<NBLK + NBG, TPB, 0, stream>>>(col, counts, E, NBLK, NBUCK,
                                                     x, W1, h1b, N, NBG);
    scan1_kernel<<<NBS, TPB, 0, stream>>>(counts, counts, bsum, L);
    scan2_kernel<<<1, 1024, 0, stream>>>(bsum, NBS);
    scatter_kernel<<<NBLK, TPB, 0, stream>>>(row, col, counts, bsum,
                                             E, NBLK, NBUCK, bucketed);
    sort_kernel<<<NBUCK, TPB, 0, stream>>>(bucketed, counts, bsum, E, NBLK, NBUCK,
                                           csr, offs, dinv, h1b, h1p, N);
    gather1_kernel<<<(N + 15) / 16, TPB, 0, stream>>>(csr, offs, h1p, dinv, b1, h2p, N);
    gather2f_kernel<<<(N + 63) / 64, TPB, 0, stream>>>(csr, offs, h2p, dinv,
                                                       W2, b2, batch, out, N);
}

// Round 13
// 369.763 us; speedup vs baseline: 1.0236x; 1.0236x over previous
//
#include <hip/hip_runtime.h>

// 2-layer GCN, CSR-gather, bf16 payloads, zero global atomics.
//   K1 [hist ∥ gemmA] -> K2 [scan1 ∥ gemmB] -> scan2 ->
//   K3 [scatter ∥ gemmC] -> sort -> gather1 -> gather2f.
// R12 lesson: scatter standalone ~55us (scattered-4B write latency), gemm
// mostly-alone ~70us -> the dependency-free gemm must be rationed across the
// WHOLE serial CSR-build chain (hist/scan1/scatter), not spent on one stage.
// Kept: 1:1 interleave (R9), 512-node buckets, packed 1-int entries,
// bf16 h1 + fused final (R10), uint-packed gathers (R11), R10-form gemm
// inner loop (R11 unroll x2 regressed).

#define TPB 256
#define CHUNK 4096          // edges per hist/scatter block
#define BK_SHIFT 9
#define NPB 512             // nodes per bucket = 1 << BK_SHIFT

__device__ __forceinline__ float bf2f(unsigned short u) {
    union { unsigned int i; float f; } v; v.i = ((unsigned int)u) << 16; return v.f;
}
__device__ __forceinline__ unsigned short f2bf(float f) {
    union { float f; unsigned int i; } v; v.f = f;
    unsigned int r = v.i + 0x7fff + ((v.i >> 16) & 1);   // RNE
    return (unsigned short)(r >> 16);
}

// role/id split for 1:1 interleaved heterogeneous grids.
// returns role (0=partner, 1=gemm) and writes id.
__device__ __forceinline__ int role_split(int b, int nPartner, int nGemm, int* id) {
    int M = min(nPartner, nGemm);
    if (b < 2 * M) { *id = b >> 1; return b & 1; }
    *id = b - M;
    return (nPartner > nGemm) ? 0 : 1;
}

// gemm role body: h1b[n] = bf16(x[n] @ W1), one thread/node, W1 staged in LDS.
__device__ __forceinline__ void gemm_role(int gid, int t, const float* __restrict__ x,
                                          const float* __restrict__ W1, float* w1s,
                                          unsigned short* __restrict__ h1b, int N) {
    for (int i = t; i < 128 * 16; i += TPB) w1s[i] = W1[i];
    __syncthreads();
    int n = gid * TPB + t;
    if (n >= N) return;
    const float4* xr = (const float4*)(x + (size_t)n * 128);
    float acc[16];
#pragma unroll
    for (int k = 0; k < 16; ++k) acc[k] = 0.f;
#pragma unroll 1
    for (int g = 0; g < 8; ++g) {
        float4 v0 = xr[g * 4 + 0], v1 = xr[g * 4 + 1];
        float4 v2 = xr[g * 4 + 2], v3 = xr[g * 4 + 3];
        float xv[16] = {v0.x, v0.y, v0.z, v0.w, v1.x, v1.y, v1.z, v1.w,
                        v2.x, v2.y, v2.z, v2.w, v3.x, v3.y, v3.z, v3.w};
#pragma unroll
        for (int cc = 0; cc < 16; ++cc) {
            const float4* w4 = (const float4*)&w1s[(g * 16 + cc) * 16];
            float4 wa = w4[0], wb = w4[1], wc = w4[2], wd = w4[3];
            float xc = xv[cc];
            acc[0]  = fmaf(xc, wa.x, acc[0]);  acc[1]  = fmaf(xc, wa.y, acc[1]);
            acc[2]  = fmaf(xc, wa.z, acc[2]);  acc[3]  = fmaf(xc, wa.w, acc[3]);
            acc[4]  = fmaf(xc, wb.x, acc[4]);  acc[5]  = fmaf(xc, wb.y, acc[5]);
            acc[6]  = fmaf(xc, wb.z, acc[6]);  acc[7]  = fmaf(xc, wb.w, acc[7]);
            acc[8]  = fmaf(xc, wc.x, acc[8]);  acc[9]  = fmaf(xc, wc.y, acc[9]);
            acc[10] = fmaf(xc, wc.z, acc[10]); acc[11] = fmaf(xc, wc.w, acc[11]);
            acc[12] = fmaf(xc, wd.x, acc[12]); acc[13] = fmaf(xc, wd.y, acc[13]);
            acc[14] = fmaf(xc, wd.z, acc[14]); acc[15] = fmaf(xc, wd.w, acc[15]);
        }
    }
    unsigned int u[8];
#pragma unroll
    for (int j = 0; j < 8; ++j)
        u[j] = (unsigned int)f2bf(acc[2 * j]) | ((unsigned int)f2bf(acc[2 * j + 1]) << 16);
    uint4* o = (uint4*)(h1b + (size_t)n * 16);
    o[0] = make_uint4(u[0], u[1], u[2], u[3]);
    o[1] = make_uint4(u[4], u[5], u[6], u[7]);
}

// K1: hist ∥ gemmA
__global__ __launch_bounds__(TPB) void hist_gemm_kernel(
        const int* __restrict__ col, int* __restrict__ counts,
        int E, int nblk, int nbuck,
        const float* __restrict__ x, const float* __restrict__ W1,
        unsigned short* __restrict__ h1b, int N, int nGemm, int gemmBase) {
    __shared__ int hist[NPB];
    __shared__ float w1s[128 * 16];
    int t = threadIdx.x, id;
    int role = role_split((int)blockIdx.x, nblk, nGemm, &id);
    if (role == 0) {
        for (int i = t; i < nbuck; i += TPB) hist[i] = 0;
        __syncthreads();
        int e0 = id * CHUNK;
        for (int i = t; i < CHUNK; i += TPB) {
            int e = e0 + i;
            if (e < E) atomicAdd(&hist[col[e] >> BK_SHIFT], 1);   // LDS atomic
        }
        __syncthreads();
        for (int i = t; i < nbuck; i += TPB) counts[i * nblk + id] = hist[i];
        return;
    }
    gemm_role(id + gemmBase, t, x, W1, w1s, h1b, N);
}

// K2: scan1 ∥ gemmB.  scan1: per-256-block exclusive scan (in place), bsum.
__global__ __launch_bounds__(TPB) void scan1_gemm_kernel(
        int* __restrict__ counts, int* __restrict__ bsum, int L, int nScan,
        const float* __restrict__ x, const float* __restrict__ W1,
        unsigned short* __restrict__ h1b, int N, int nGemm, int gemmBase) {
    __shared__ float w1s[128 * 16];
    __shared__ int s[TPB];
    int t = threadIdx.x, id;
    int role = role_split((int)blockIdx.x, nScan, nGemm, &id);
    if (role == 0) {
        int i = id * TPB + t;
        int d = (i < L) ? counts[i] : 0;
        s[t] = d; __syncthreads();
        for (int off = 1; off < TPB; off <<= 1) {
            int v = (t >= off) ? s[t - off] : 0;
            __syncthreads();
            s[t] += v;
            __syncthreads();
        }
        if (i < L) counts[i] = s[t] - d;
        if (t == TPB - 1) bsum[id] = s[t];
        return;
    }
    gemm_role(id + gemmBase, t, x, W1, w1s, h1b, N);
}

// scan2: single-block exclusive scan of up to 2048 block sums (2 elems/thread)
__global__ __launch_bounds__(1024) void scan2_kernel(int* __restrict__ bsum, int nb) {
    __shared__ int s[1024];
    int t = threadIdx.x;
    int i0 = t * 2, i1 = t * 2 + 1;
    int v0 = (i0 < nb) ? bsum[i0] : 0;
    int v1 = (i1 < nb) ? bsum[i1] : 0;
    int pv = v0 + v1;
    s[t] = pv; __syncthreads();
    for (int off = 1; off < 1024; off <<= 1) {
        int u = (t >= off) ? s[t - off] : 0;
        __syncthreads();
        s[t] += u;
        __syncthreads();
    }
    int exc = s[t] - pv;
    if (i0 < nb) bsum[i0] = exc;
    if (i1 < nb) bsum[i1] = exc + v0;
}

// cbase[f] = counts[f] + bsum[f>>8]
__device__ __forceinline__ int cbase_at(const int* counts, const int* bsum, int f) {
    return counts[f] + bsum[f >> 8];
}

// K3: scatter ∥ gemmC.  Scatter: bucketed[pos] = (local_col<<18)|row.
__global__ __launch_bounds__(TPB) void scatter_gemm_kernel(
        const int* __restrict__ row, const int* __restrict__ col,
        const int* __restrict__ counts, const int* __restrict__ bsum,
        int E, int nblk, int nbuck, int* __restrict__ bucketed,
        const float* __restrict__ x, const float* __restrict__ W1,
        unsigned short* __restrict__ h1b, int N, int nGemm, int gemmBase) {
    __shared__ int cur[NPB];
    __shared__ float w1s[128 * 16];
    int t = threadIdx.x, id;
    int role = role_split((int)blockIdx.x, nblk, nGemm, &id);
    if (role == 0) {
        for (int i = t; i < nbuck; i += TPB)
            cur[i] = cbase_at(counts, bsum, i * nblk + id);
        __syncthreads();
        int e0 = id * CHUNK;
        for (int i = t; i < CHUNK; i += TPB) {
            int e = e0 + i;
            if (e < E) {
                int c = col[e];
                int pos = atomicAdd(&cur[c >> BK_SHIFT], 1);   // LDS atomic
                bucketed[pos] = ((c & (NPB - 1)) << 18) | row[e];
            }
        }
        return;
    }
    gemm_role(id + gemmBase, t, x, W1, w1s, h1b, N);
}

// sort: one block per 512-node bucket: counting sort, emit csr/offs/dinv,
// h1p = bf16(dinv * h1b).
__global__ __launch_bounds__(TPB) void sort_kernel(
        const int* __restrict__ bucketed,
        const int* __restrict__ counts, const int* __restrict__ bsum,
        int E, int nblk, int nbuck,
        int* __restrict__ csr, int* __restrict__ offs, float* __restrict__ dinv,
        const unsigned short* __restrict__ h1b, unsigned short* __restrict__ h1p, int N) {
    __shared__ int lhist[NPB];
    __shared__ int part[TPB];
    __shared__ float sdinv[NPB];
    int bk = blockIdx.x, t = threadIdx.x;
    int n0 = bk << BK_SHIFT;
    int n1 = min(n0 + NPB, N);
    int e0 = cbase_at(counts, bsum, bk * nblk);
    int e1 = (bk + 1 < nbuck) ? cbase_at(counts, bsum, (bk + 1) * nblk) : E;

    lhist[t] = 0; lhist[t + TPB] = 0;
    __syncthreads();
    for (int i = e0 + t; i < e1; i += TPB)
        atomicAdd(&lhist[bucketed[i] >> 18], 1);               // LDS atomic
    __syncthreads();

    int base = t * 2;
    int c0 = lhist[base], c1 = lhist[base + 1];
    int s = c0 + c1;
    part[t] = s;
    __syncthreads();
    for (int off = 1; off < TPB; off <<= 1) {
        int v = (t >= off) ? part[t - off] : 0;
        __syncthreads();
        part[t] += v;
        __syncthreads();
    }
    int o0 = e0 + part[t] - s;
    int o1 = o0 + c0;
    lhist[base] = o0; lhist[base + 1] = o1;
    sdinv[base]     = rsqrtf((float)c0 + 1.0f);
    sdinv[base + 1] = rsqrtf((float)c1 + 1.0f);
    int n = n0 + base;
    if (n + 0 < N) { offs[n + 0] = o0; dinv[n + 0] = sdinv[base]; }
    if (n + 1 < N) { offs[n + 1] = o1; dinv[n + 1] = sdinv[base + 1]; }
    __syncthreads();

    for (int i = e0 + t; i < e1; i += TPB) {
        int v = bucketed[i];
        int pos = atomicAdd(&lhist[v >> 18], 1);               // LDS atomic
        csr[pos] = v & 0x3FFFF;
    }
    int nq = (n1 - n0) * 4;                  // one quad (4 feats) per i
    for (int i = t; i < nq; i += TPB) {
        float dv = sdinv[i >> 2];
        uint2 u = ((const uint2*)h1b)[(size_t)n0 * 4 + i];
        float f0 = bf2f((unsigned short)(u.x & 0xffff));
        float f1 = bf2f((unsigned short)(u.x >> 16));
        float f2 = bf2f((unsigned short)(u.y & 0xffff));
        float f3 = bf2f((unsigned short)(u.y >> 16));
        ((ushort4*)h1p)[(size_t)n0 * 4 + i] =
            make_ushort4(f2bf(f0 * dv), f2bf(f1 * dv), f2bf(f2 * dv), f2bf(f3 * dv));
    }
    if (bk == 0 && t == 0) offs[N] = E;
}

// gather1: 16 lanes/node; uint-packed loads (2 edges per load instr per group);
// 32 edges/iteration; cross-half shfl_xor reduce.
__global__ __launch_bounds__(TPB) void gather1_kernel(const int* __restrict__ csr,
                                                      const int* __restrict__ offs,
                                                      const unsigned short* __restrict__ h1p,
                                                      const float* __restrict__ dinv,
                                                      const float* __restrict__ b1,
                                                      unsigned short* __restrict__ h2p, int N) {
    int t = threadIdx.x;
    int c = blockIdx.x * 16 + (t >> 4);
    int lane = t & 15;
    int half = lane >> 3;                    // which edge of the pair
    int kk = lane & 7;                       // feature pair: 2kk, 2kk+1
    if (c >= N) return;
    int p0 = offs[c], p1 = offs[c + 1];
    float a0 = 0.f, a1 = 0.f;
    for (int p = p0; p < p1; p += 32) {
        int s_lo = csr[min(p + lane, p1 - 1)];
        int s_hi = csr[min(p + 16 + lane, p1 - 1)];
        int rem = p1 - p;
        unsigned int u[16];
#pragma unroll
        for (int j = 0; j < 8; ++j) {
            int sj = __shfl(s_lo, 2 * j + half, 16);
            u[j] = *(const unsigned int*)&h1p[(size_t)sj * 16 + 2 * kk];
        }
#pragma unroll
        for (int j = 8; j < 16; ++j) {
            int sj = __shfl(s_hi, 2 * j + half - 16, 16);
            u[j] = *(const unsigned int*)&h1p[(size_t)sj * 16 + 2 * kk];
        }
#pragma unroll
        for (int j = 0; j < 16; ++j) {
            bool ok = (2 * j + half) < rem;
            a0 += ok ? bf2f((unsigned short)(u[j] & 0xffff)) : 0.f;
            a1 += ok ? bf2f((unsigned short)(u[j] >> 16)) : 0.f;
        }
    }
    a0 += __shfl_xor(a0, 8, 16);
    a1 += __shfl_xor(a1, 8, 16);
    if (half == 0) {
        float dc = dinv[c];
        unsigned int us = *(const unsigned int*)&h1p[(size_t)c * 16 + 2 * kk];
        float s0 = bf2f((unsigned short)(us & 0xffff));
        float s1 = bf2f((unsigned short)(us >> 16));
        float r0 = fmaf(dc, a0 + s0, b1[2 * kk]);
        float r1 = fmaf(dc, a1 + s1, b1[2 * kk + 1]);
        r0 = dc * fmaxf(r0, 0.f);
        r1 = dc * fmaxf(r1, 0.f);
        unsigned int w = (unsigned int)f2bf(r0) | ((unsigned int)f2bf(r1) << 16);
        *(unsigned int*)&h2p[(size_t)c * 16 + 2 * kk] = w;
    }
}

// gather2f: fused gather2 + W2 matmul + sorted-batch pooling.  Block = 64 nodes.
__global__ __launch_bounds__(TPB) void gather2f_kernel(
        const int* __restrict__ csr, const int* __restrict__ offs,
        const unsigned short* __restrict__ h2p, const float* __restrict__ dinv,
        const float* __restrict__ W2, const float* __restrict__ b2,
        const int* __restrict__ batch, float* __restrict__ out, int N) {
    __shared__ float w2s[16 * 64];
    __shared__ float asT[64 * 17];
    __shared__ float pool[64];
    int t = threadIdx.x;
    for (int i = t; i < 16 * 64; i += TPB) w2s[i] = W2[i];
    if (t < 64) pool[t] = 0.f;

    int n0 = blockIdx.x * 64;
    int nLast = min(n0 + 63, N - 1);
    int g0 = batch[n0];
    bool uniform = (batch[nLast] == g0);     // batch sorted

    // phase 1: gather (4 nodes per 16-lane group), uint-packed loads
    int grp = t >> 4, lane = t & 15;
    int half = lane >> 3, kk = lane & 7;
#pragma unroll 1
    for (int it = 0; it < 4; ++it) {
        int m = grp * 4 + it;
        int c = n0 + m;
        if (c < N) {
            int p0 = offs[c], p1 = offs[c + 1];
            float a0 = 0.f, a1 = 0.f;
            for (int p = p0; p < p1; p += 32) {
                int s_lo = csr[min(p + lane, p1 - 1)];
                int s_hi = csr[min(p + 16 + lane, p1 - 1)];
                int rem = p1 - p;
                unsigned int u[16];
#pragma unroll
                for (int j = 0; j < 8; ++j) {
                    int sj = __shfl(s_lo, 2 * j + half, 16);
                    u[j] = *(const unsigned int*)&h2p[(size_t)sj * 16 + 2 * kk];
                }
#pragma unroll
                for (int j = 8; j < 16; ++j) {
                    int sj = __shfl(s_hi, 2 * j + half - 16, 16);
                    u[j] = *(const unsigned int*)&h2p[(size_t)sj * 16 + 2 * kk];
                }
#pragma unroll
                for (int j = 0; j < 16; ++j) {
                    bool ok = (2 * j + half) < rem;
                    a0 += ok ? bf2f((unsigned short)(u[j] & 0xffff)) : 0.f;
                    a1 += ok ? bf2f((unsigned short)(u[j] >> 16)) : 0.f;
                }
            }
            a0 += __shfl_xor(a0, 8, 16);
            a1 += __shfl_xor(a1, 8, 16);
            if (half == 0) {
                float dc = dinv[c];
                unsigned int us = *(const unsigned int*)&h2p[(size_t)c * 16 + 2 * kk];
                float s0 = bf2f((unsigned short)(us & 0xffff));
                float s1 = bf2f((unsigned short)(us >> 16));
                asT[m * 17 + 2 * kk]     = dc * (a0 + s0);
                asT[m * 17 + 2 * kk + 1] = dc * (a1 + s1);
            }
        }
    }
    __syncthreads();

    // phase 2: wave w covers nodes n0+16w .. n0+16w+15
    int wave = t >> 6, j = t & 63;
    float w2reg[16];
#pragma unroll
    for (int kx = 0; kx < 16; ++kx) w2reg[kx] = w2s[kx * 64 + j];
    float b2j = b2[j];
    float val = 0.f;
    int g_cur = -1;
#pragma unroll 1
    for (int mi = 0; mi < 16; ++mi) {
        int m = wave * 16 + mi;
        int c = n0 + m;
        if (c >= N) break;
        const float* ar = &asT[m * 17];
        float y = b2j;
#pragma unroll
        for (int kx = 0; kx < 16; ++kx) y = fmaf(ar[kx], w2reg[kx], y);
        if (uniform) {
            val += y;
        } else {
            int g = batch[c];
            if (g != g_cur) {
                if (g_cur >= 0) atomicAdd(&out[(size_t)g_cur * 64 + j], val);
                val = 0.f;
                g_cur = g;
            }
            val += y;
        }
    }
    if (uniform) {
        atomicAdd(&pool[j], val);            // LDS, 4-way per address
        __syncthreads();
        if (t < 64) atomicAdd(&out[(size_t)g0 * 64 + t], pool[t]);
    } else {
        if (g_cur >= 0) atomicAdd(&out[(size_t)g_cur * 64 + j], val);
    }
}

static inline size_t align64(size_t v) { return (v + 63) & ~(size_t)63; }

extern "C" void kernel_launch(void* const* d_in, const int* in_sizes, int n_in,
                              void* d_out, int out_size, void* d_ws, size_t ws_size,
                              hipStream_t stream) {
    const float* x     = (const float*)d_in[0];
    const int*   ei    = (const int*)d_in[1];
    const int*   batch = (const int*)d_in[2];
    const float* W1    = (const float*)d_in[3];
    const float* b1    = (const float*)d_in[4];
    const float* W2    = (const float*)d_in[5];
    const float* b2    = (const float*)d_in[6];

    const int N = in_sizes[0] / 128;
    const int E = in_sizes[1] / 2;
    const int* row = ei;        // edge_index[0]
    const int* col = ei + E;    // edge_index[1]

    const int NBLK  = (E + CHUNK - 1) / CHUNK;       // 782
    const int NBUCK = (N + NPB - 1) / NPB;           // 391 (<=512)
    const int L     = NBUCK * NBLK;                  // 305762
    const int NBS   = (L + TPB - 1) / TPB;           // 1195 (<=2048 for scan2)
    const int NBG   = (N + TPB - 1) / TPB;           // 782

    // gemm slices: small ones hide under hist/scan1; the bulk pairs with scatter
    int NA = NBG < 128 ? NBG : 128;
    int NB_ = (NBG - NA) < 128 ? (NBG - NA) : 128;
    int NC = NBG - NA - NB_;

    char* p = (char*)d_ws;
    int*            counts   = (int*)p;            p += align64((size_t)L * 4);
    int*            bsum     = (int*)p;            p += align64(2048 * 4);
    int*            bucketed = (int*)p;            p += align64((size_t)E * 4);
    int*            csr      = (int*)p;            p += align64((size_t)E * 4);
    int*            offs     = (int*)p;            p += align64((size_t)(N + 1) * 4);
    float*          dinv     = (float*)p;          p += align64((size_t)N * 4);
    unsigned short* h1b      = (unsigned short*)p; p += align64((size_t)N * 16 * 2);
    unsigned short* h1p      = (unsigned short*)p; p += align64((size_t)N * 16 * 2);
    unsigned short* h2p      = (unsigned short*)p; p += align64((size_t)N * 16 * 2);
    float*          out      = (float*)d_out;

    hipMemsetAsync(out, 0, (size_t)out_size * sizeof(float), stream);

    hist_gemm_kernel<<<NBLK + NA, TPB, 0, stream>>>(col, counts, E, NBLK, NBUCK,
                                                    x, W1, h1b, N, NA, 0);
    scan1_gemm_kernel<<<NBS + NB_, TPB, 0, stream>>>(counts, bsum, L, NBS,
                                                     x, W1, h1b, N, NB_, NA);
    scan2_kernel<<<1, 1024, 0, stream>>>(bsum, NBS);
    scatter_gemm_kernel<<<NBLK + NC, TPB, 0, stream>>>(row, col, counts, bsum,
                                                       E, NBLK, NBUCK, bucketed,
                                                       x, W1, h1b, N, NC, NA + NB_);
    sort_kernel<<<NBUCK, TPB, 0, stream>>>(bucketed, counts, bsum, E, NBLK, NBUCK,
                                           csr, offs, dinv, h1b, h1p, N);
    gather1_kernel<<<(N + 15) / 16, TPB, 0, stream>>>(csr, offs, h1p, dinv, b1, h2p, N);
    gather2f_kernel<<<(N + 63) / 64, TPB, 0, stream>>>(csr, offs, h2p, dinv,
                                                       W2, b2, batch, out, N);
}